// Round 6
// baseline (239.482 us; speedup 1.0000x reference)
//
#include <hip/hip_runtime.h>
#include <cstdint>

typedef __attribute__((ext_vector_type(8))) short bf16x8;
typedef __attribute__((ext_vector_type(4))) float f32x4;

#if __has_builtin(__builtin_amdgcn_exp2f)
#define EXP2F(x) __builtin_amdgcn_exp2f(x)
#else
#define EXP2F(x) exp2f(x)
#endif
#if __has_builtin(__builtin_amdgcn_rcpf)
#define RCPF(x) __builtin_amdgcn_rcpf(x)
#else
#define RCPF(x) (1.0f/(x))
#endif

#define C2LOG2E 2.885390081777927f   // 2*log2(e)
#define LOG2E   1.4426950408889634f

__device__ __forceinline__ unsigned int f2bf(float f) {
    union { float f; unsigned int u; } v; v.f = f;
    return ((v.u + 0x7FFFu + ((v.u >> 16) & 1u)) >> 16);
}
__device__ __forceinline__ float bf2f(unsigned short h) {
    union { unsigned int u; float f; } v; v.u = ((unsigned int)h) << 16; return v.f;
}

// ---- prep: X fp32->bf16 ; transpose W_ap, W_pa, W_po ----
__global__ void prep_kernel(const float* __restrict__ x, const float* __restrict__ W_ap,
                            const float* __restrict__ W_pa, const float* __restrict__ W_po,
                            unsigned short* __restrict__ Xb, float* __restrict__ Wt,
                            float* __restrict__ Wpat, float* __restrict__ Wpot) {
    int t = blockIdx.x * 256 + threadIdx.x;   // 32768 threads, 8 elems each
    const float* src = x + (size_t)t * 8;
    float4 a = *(const float4*)(src);
    float4 b = *(const float4*)(src + 4);
    unsigned int p0 = f2bf(a.x) | (f2bf(a.y) << 16);
    unsigned int p1 = f2bf(a.z) | (f2bf(a.w) << 16);
    unsigned int p2 = f2bf(b.x) | (f2bf(b.y) << 16);
    unsigned int p3 = f2bf(b.z) | (f2bf(b.w) << 16);
    *(int4*)(Xb + (size_t)t * 8) = make_int4((int)p0, (int)p1, (int)p2, (int)p3);
    if (t < 64 * 64) {
        int src_i = (t & 63) * 64 + (t >> 6);   // [d][o] -> [o][d]
        Wt[t]   = W_ap[src_i];
        Wpat[t] = W_pa[src_i];
        Wpot[t] = W_po[src_i];
    }
}

// ---- main: one block per (b,i); 4 waves j-split; 2 barriers ----
// launch_bounds(256,8): 8 blocks/CU = 32 waves/CU, VGPR cap 64 (R4 body fits 64).
__global__ __launch_bounds__(256, 8) void gat_kernel(
    const float* __restrict__ x, const float* __restrict__ b_ap, const float* __restrict__ att_w,
    const float* __restrict__ b_pa, const float* __restrict__ b_po,
    const float* __restrict__ gma, const float* __restrict__ bta,
    const float* __restrict__ rmean, const float* __restrict__ rvar,
    const unsigned short* __restrict__ Xb, const float* __restrict__ Wt,
    const float* __restrict__ Wpat, const float* __restrict__ Wpot,
    float* __restrict__ out)
{
    __shared__ float sSc[512];       // scores -> p (block-shared)
    __shared__ float sAgP[4 * 64];   // per-wave agg partials

    const int t  = threadIdx.x;
    const int l  = t & 63;
    const int w  = t >> 6;
    const int ig = blockIdx.x;                 // global i in [0,4096)
    const int b  = ig >> 9;
    const int lm = l & 15;                     // col-in-tile
    const int lq = l >> 4;                     // quarter
    const unsigned short* __restrict__ Xg = Xb + (size_t)b * (512 * 64);
    const float* __restrict__ xi = x + (size_t)ig * 64;

    // ---- A-fragments (W_i^T) in-register (redundant per wave, L1-hot) ----
    bf16x8 af[8];
    #pragma unroll
    for (int ks = 0; ks < 2; ++ks) {
        float4 xc0 = *(const float4*)(xi + ks * 32 + lq * 8);
        float4 xc1 = *(const float4*)(xi + ks * 32 + lq * 8 + 4);
        #pragma unroll
        for (int of = 0; of < 4; ++of) {
            const float* wr = Wt + (of * 16 + lm) * 64 + ks * 32 + lq * 8;
            float4 w0 = *(const float4*)(wr);
            float4 w1 = *(const float4*)(wr + 4);
            unsigned int p0 = f2bf(w0.x * xc0.x) | (f2bf(w0.y * xc0.y) << 16);
            unsigned int p1 = f2bf(w0.z * xc0.z) | (f2bf(w0.w * xc0.w) << 16);
            unsigned int p2 = f2bf(w1.x * xc1.x) | (f2bf(w1.y * xc1.y) << 16);
            unsigned int p3 = f2bf(w1.z * xc1.z) | (f2bf(w1.w * xc1.w) << 16);
            int4 pk = make_int4((int)p0, (int)p1, (int)p2, (int)p3);
            af[of * 2 + ks] = *reinterpret_cast<bf16x8*>(&pk);
        }
    }

    // ---- per-lane o-constants (o = of*16 + lq*4 + r) ----
    float n2a[16], cb[16];
    float asum = 0.f;
    #pragma unroll
    for (int of = 0; of < 4; ++of) {
        #pragma unroll
        for (int r = 0; r < 4; ++r) {
            int o = of * 16 + lq * 4 + r;
            float a = att_w[o];
            n2a[of * 4 + r] = -2.f * a;
            cb[of * 4 + r]  = C2LOG2E * b_ap[o];
            asum += a;
        }
    }

    // ---- GEMM + tanh-score: this wave's 8 j-tiles [8w, 8w+8) ----
    const unsigned short* xrow = Xg + lm * 64 + lq * 8;
    const int jt0 = w * 8;
    bf16x8 nb0 = *(const bf16x8*)(xrow + jt0 * 1024);
    bf16x8 nb1 = *(const bf16x8*)(xrow + jt0 * 1024 + 32);
    for (int jj = 0; jj < 8; ++jj) {
        int jt = jt0 + jj;
        bf16x8 b0 = nb0, b1 = nb1;
        if (jj < 7) {
            nb0 = *(const bf16x8*)(xrow + (jt + 1) * 1024);
            nb1 = *(const bf16x8*)(xrow + (jt + 1) * 1024 + 32);
        }
        f32x4 acc[4];
        #pragma unroll
        for (int of = 0; of < 4; ++of) {
            acc[of] = (f32x4){0.f, 0.f, 0.f, 0.f};
            acc[of] = __builtin_amdgcn_mfma_f32_16x16x32_bf16(af[of * 2],     b0, acc[of], 0, 0, 0);
            acc[of] = __builtin_amdgcn_mfma_f32_16x16x32_bf16(af[of * 2 + 1], b1, acc[of], 0, 0, 0);
        }
        float p4[4];
        #pragma unroll
        for (int of = 0; of < 4; ++of) {
            float pp = 0.f;
            #pragma unroll
            for (int r = 0; r < 4; ++r) {
                float e = EXP2F(fmaf(acc[of][r], C2LOG2E, cb[of * 4 + r]));
                pp = fmaf(n2a[of * 4 + r], RCPF(1.f + e), pp);
            }
            p4[of] = pp;
        }
        float part = asum + ((p4[0] + p4[1]) + (p4[2] + p4[3]));
        part += __shfl_xor(part, 16);
        part += __shfl_xor(part, 32);
        if (l < 16) sSc[jt * 16 + l] = part;
    }
    __syncthreads();                 // barrier 1: all 512 scores in LDS

    // ---- softmax over 512 (redundant per wave; lane l holds j = l*8..l*8+7) ----
    float s0[8];
    {
        float4 r0 = *(const float4*)(sSc + l * 8);
        float4 r1 = *(const float4*)(sSc + l * 8 + 4);
        s0[0] = r0.x; s0[1] = r0.y; s0[2] = r0.z; s0[3] = r0.w;
        s0[4] = r1.x; s0[5] = r1.y; s0[6] = r1.z; s0[7] = r1.w;
    }
    float m = s0[0];
    #pragma unroll
    for (int e = 1; e < 8; ++e) m = fmaxf(m, s0[e]);
    #pragma unroll
    for (int o2 = 32; o2; o2 >>= 1) m = fmaxf(m, __shfl_xor(m, o2));
    float sm = 0.f;
    #pragma unroll
    for (int e = 0; e < 8; ++e) { s0[e] = EXP2F((s0[e] - m) * LOG2E); sm += s0[e]; }
    #pragma unroll
    for (int o2 = 32; o2; o2 >>= 1) sm += __shfl_xor(sm, o2);
    float inv = RCPF(sm);
    // writeback p for THIS wave's j-quarter only: lanes [16w,16w+16) own j=[128w,128w+128)
    if ((l >> 4) == w) {
        float4 r0 = {s0[0] * inv, s0[1] * inv, s0[2] * inv, s0[3] * inv};
        float4 r1 = {s0[4] * inv, s0[5] * inv, s0[6] * inv, s0[7] * inv};
        *(float4*)(sSc + l * 8) = r0;
        *(float4*)(sSc + l * 8 + 4) = r1;
    }
    asm volatile("s_waitcnt lgkmcnt(0)" ::: "memory");   // wave-private RAW on own quarter

    // ---- agg partial over this wave's 128 j's ----
    {
        const int rs = l >> 3, c8 = (l & 7) * 8;
        float a8[8];
        #pragma unroll
        for (int e = 0; e < 8; ++e) a8[e] = 0.f;
        #pragma unroll 4
        for (int jb = 0; jb < 16; ++jb) {
            int j = w * 128 + jb * 8 + rs;
            float pj = sSc[j];
            bf16x8 v = *(const bf16x8*)(Xg + j * 64 + c8);
            #pragma unroll
            for (int e = 0; e < 8; ++e)
                a8[e] = fmaf(bf2f((unsigned short)v[e]), pj, a8[e]);
        }
        #pragma unroll
        for (int e = 0; e < 8; ++e) {
            float v = a8[e];
            v += __shfl_xor(v, 8);
            v += __shfl_xor(v, 16);
            v += __shfl_xor(v, 32);
            a8[e] = v;
        }
        if (l < 8) {
            #pragma unroll
            for (int e = 0; e < 8; ++e) sAgP[w * 64 + l * 8 + e] = a8[e];
        }
    }
    __syncthreads();                 // barrier 2: all agg partials in LDS

    // ---- epilogue on wave 0: h[o=l] = agg@W_pa + x_i@W_po + biases ; BN ; SELU ----
    if (w == 0) {
        float hv = b_pa[l] + b_po[l];
        const float* wa = Wpat + l * 64;
        const float* wo = Wpot + l * 64;
        #pragma unroll 4
        for (int dc = 0; dc < 16; ++dc) {
            float4 g0 = *(const float4*)(sAgP +       dc * 4);
            float4 g1 = *(const float4*)(sAgP +  64 + dc * 4);
            float4 g2 = *(const float4*)(sAgP + 128 + dc * 4);
            float4 g3 = *(const float4*)(sAgP + 192 + dc * 4);
            float4 ag = {g0.x + g1.x + g2.x + g3.x, g0.y + g1.y + g2.y + g3.y,
                         g0.z + g1.z + g2.z + g3.z, g0.w + g1.w + g2.w + g3.w};
            float4 va = *(const float4*)(wa + dc * 4);
            float4 vo = *(const float4*)(wo + dc * 4);
            float4 xv = *(const float4*)(xi + dc * 4);
            hv = fmaf(ag.x, va.x, hv); hv = fmaf(ag.y, va.y, hv);
            hv = fmaf(ag.z, va.z, hv); hv = fmaf(ag.w, va.w, hv);
            hv = fmaf(xv.x, vo.x, hv); hv = fmaf(xv.y, vo.y, hv);
            hv = fmaf(xv.z, vo.z, hv); hv = fmaf(xv.w, vo.w, hv);
        }
        float istd = rsqrtf(rvar[l] + 1e-5f);
        hv = (hv - rmean[l]) * istd * gma[l] + bta[l];
        const float alpha = 1.6732632423543772f, scale = 1.0507009873554805f;
        float neg = alpha * (EXP2F(hv * LOG2E) - 1.0f);
        out[(size_t)ig * 64 + l] = scale * (hv > 0.f ? hv : neg);
    }
}

extern "C" void kernel_launch(void* const* d_in, const int* in_sizes, int n_in,
                              void* d_out, int out_size, void* d_ws, size_t ws_size,
                              hipStream_t stream) {
    const float* x     = (const float*)d_in[0];
    const float* W_ap  = (const float*)d_in[1];
    const float* b_ap  = (const float*)d_in[2];
    const float* att_w = (const float*)d_in[3];
    const float* W_pa  = (const float*)d_in[4];
    const float* b_pa  = (const float*)d_in[5];
    const float* W_po  = (const float*)d_in[6];
    const float* b_po  = (const float*)d_in[7];
    const float* gma   = (const float*)d_in[8];
    const float* bta   = (const float*)d_in[9];
    const float* rmean = (const float*)d_in[10];
    const float* rvar  = (const float*)d_in[11];

    char* ws = (char*)d_ws;
    unsigned short* Xb = (unsigned short*)ws;          // 512 KB bf16 X
    float* Wt          = (float*)(ws + 512 * 1024);    // 16 KB W_ap^T
    float* Wpat        = (float*)(ws + 528 * 1024);    // 16 KB W_pa^T
    float* Wpot        = (float*)(ws + 544 * 1024);    // 16 KB W_po^T
    float* out         = (float*)d_out;

    prep_kernel<<<128, 256, 0, stream>>>(x, W_ap, W_pa, W_po, Xb, Wt, Wpat, Wpot);
    gat_kernel<<<4096, 256, 0, stream>>>(x, b_ap, att_w, b_pa, b_po, gma, bta, rmean, rvar,
                                         Xb, Wt, Wpat, Wpot, out);
}

// Round 7
// 155.954 us; speedup vs baseline: 1.5356x; 1.5356x over previous
//
#include <hip/hip_runtime.h>
#include <cstdint>

typedef __attribute__((ext_vector_type(8))) short bf16x8;
typedef __attribute__((ext_vector_type(4))) float f32x4;

#if __has_builtin(__builtin_amdgcn_exp2f)
#define EXP2F(x) __builtin_amdgcn_exp2f(x)
#else
#define EXP2F(x) exp2f(x)
#endif
#if __has_builtin(__builtin_amdgcn_rcpf)
#define RCPF(x) __builtin_amdgcn_rcpf(x)
#else
#define RCPF(x) (1.0f/(x))
#endif

#define C2LOG2E 2.885390081777927f   // 2*log2(e)
#define LOG2E   1.4426950408889634f

__device__ __forceinline__ unsigned int f2bf(float f) {
    union { float f; unsigned int u; } v; v.f = f;
    return ((v.u + 0x7FFFu + ((v.u >> 16) & 1u)) >> 16);
}
__device__ __forceinline__ float bf2f(unsigned short h) {
    union { unsigned int u; float f; } v; v.u = ((unsigned int)h) << 16; return v.f;
}

// ---- prep: X fp32->bf16 ; transpose W_ap, W_pa, W_po ----
__global__ void prep_kernel(const float* __restrict__ x, const float* __restrict__ W_ap,
                            const float* __restrict__ W_pa, const float* __restrict__ W_po,
                            unsigned short* __restrict__ Xb, float* __restrict__ Wt,
                            float* __restrict__ Wpat, float* __restrict__ Wpot) {
    int t = blockIdx.x * 256 + threadIdx.x;   // 32768 threads, 8 elems each
    const float* src = x + (size_t)t * 8;
    float4 a = *(const float4*)(src);
    float4 b = *(const float4*)(src + 4);
    unsigned int p0 = f2bf(a.x) | (f2bf(a.y) << 16);
    unsigned int p1 = f2bf(a.z) | (f2bf(a.w) << 16);
    unsigned int p2 = f2bf(b.x) | (f2bf(b.y) << 16);
    unsigned int p3 = f2bf(b.z) | (f2bf(b.w) << 16);
    *(int4*)(Xb + (size_t)t * 8) = make_int4((int)p0, (int)p1, (int)p2, (int)p3);
    if (t < 64 * 64) {
        int src_i = (t & 63) * 64 + (t >> 6);   // [d][o] -> [o][d]
        Wt[t]   = W_ap[src_i];
        Wpat[t] = W_pa[src_i];
        Wpot[t] = W_po[src_i];
    }
}

// ---- main: one block per (b,i); 4 waves split over the o-dim (16 o's each).
// Wave body ~40-48 unified regs -> fits the (256,8) 64-reg cap WITHOUT spills,
// giving 8 waves/SIMD. (R5 failed because its ~80-reg body was capped to 64.)
__global__ __launch_bounds__(256, 8) void gat_kernel(
    const float* __restrict__ x, const float* __restrict__ b_ap, const float* __restrict__ att_w,
    const float* __restrict__ b_pa, const float* __restrict__ b_po,
    const float* __restrict__ gma, const float* __restrict__ bta,
    const float* __restrict__ rmean, const float* __restrict__ rvar,
    const unsigned short* __restrict__ Xb, const float* __restrict__ Wt,
    const float* __restrict__ Wpat, const float* __restrict__ Wpot,
    float* __restrict__ out)
{
    __shared__ float sScP[4 * 512];  // per-o-group score partials
    __shared__ float sP[512];        // normalized p
    __shared__ float sAgP[4 * 64];   // per-wave agg partials

    const int t  = threadIdx.x;
    const int l  = t & 63;
    const int w  = t >> 6;                     // o-group AND agg j-quarter owner
    const int ig = blockIdx.x;                 // global i in [0,4096)
    const int b  = ig >> 9;
    const int lm = l & 15;
    const int lq = l >> 4;
    const unsigned short* __restrict__ Xg = Xb + (size_t)b * (512 * 64);
    const float* __restrict__ xi = x + (size_t)ig * 64;

    // ---- A-fragments for THIS wave's 16 o's only: af[ks], rows o = w*16+lm ----
    bf16x8 af[2];
    #pragma unroll
    for (int ks = 0; ks < 2; ++ks) {
        float4 xc0 = *(const float4*)(xi + ks * 32 + lq * 8);
        float4 xc1 = *(const float4*)(xi + ks * 32 + lq * 8 + 4);
        const float* wr = Wt + (w * 16 + lm) * 64 + ks * 32 + lq * 8;
        float4 w0 = *(const float4*)(wr);
        float4 w1 = *(const float4*)(wr + 4);
        unsigned int p0 = f2bf(w0.x * xc0.x) | (f2bf(w0.y * xc0.y) << 16);
        unsigned int p1 = f2bf(w0.z * xc0.z) | (f2bf(w0.w * xc0.w) << 16);
        unsigned int p2 = f2bf(w1.x * xc1.x) | (f2bf(w1.y * xc1.y) << 16);
        unsigned int p3 = f2bf(w1.z * xc1.z) | (f2bf(w1.w * xc1.w) << 16);
        int4 pk = make_int4((int)p0, (int)p1, (int)p2, (int)p3);
        af[ks] = *reinterpret_cast<bf16x8*>(&pk);
    }

    // ---- per-lane constants for 4 o's: o = w*16 + lq*4 + r ----
    float n2a[4], cb[4];
    float asum = 0.f;
    #pragma unroll
    for (int r = 0; r < 4; ++r) {
        int o = w * 16 + lq * 4 + r;
        float a = att_w[o];
        n2a[r] = -2.f * a;
        cb[r]  = C2LOG2E * b_ap[o];
        asum += a;
    }

    // ---- all 32 j-tiles: 2 MFMA + 4-elem tanh-score partial ----
    for (int jt = 0; jt < 32; ++jt) {
        const unsigned short* xrow = Xg + (jt * 16 + lm) * 64 + lq * 8;
        bf16x8 b0 = *(const bf16x8*)(xrow);
        bf16x8 b1 = *(const bf16x8*)(xrow + 32);
        f32x4 acc = (f32x4){0.f, 0.f, 0.f, 0.f};
        acc = __builtin_amdgcn_mfma_f32_16x16x32_bf16(af[0], b0, acc, 0, 0, 0);
        acc = __builtin_amdgcn_mfma_f32_16x16x32_bf16(af[1], b1, acc, 0, 0, 0);
        float part = asum;
        #pragma unroll
        for (int r = 0; r < 4; ++r) {
            float e = EXP2F(fmaf(acc[r], C2LOG2E, cb[r]));
            part = fmaf(n2a[r], RCPF(1.f + e), part);
        }
        part += __shfl_xor(part, 16);
        part += __shfl_xor(part, 32);
        if (l < 16) sScP[w * 512 + jt * 16 + l] = part;
    }
    __syncthreads();                 // barrier 1: all score partials in LDS

    // ---- softmax over 512 (redundant per wave; lane l holds j = l*8..l*8+7) ----
    float s0[8];
    #pragma unroll
    for (int e = 0; e < 8; ++e) s0[e] = 0.f;
    #pragma unroll
    for (int wa = 0; wa < 4; ++wa) {
        float4 a0 = *(const float4*)(sScP + wa * 512 + l * 8);
        float4 a1 = *(const float4*)(sScP + wa * 512 + l * 8 + 4);
        s0[0] += a0.x; s0[1] += a0.y; s0[2] += a0.z; s0[3] += a0.w;
        s0[4] += a1.x; s0[5] += a1.y; s0[6] += a1.z; s0[7] += a1.w;
    }
    float m = s0[0];
    #pragma unroll
    for (int e = 1; e < 8; ++e) m = fmaxf(m, s0[e]);
    #pragma unroll
    for (int o2 = 32; o2; o2 >>= 1) m = fmaxf(m, __shfl_xor(m, o2));
    float sm = 0.f;
    #pragma unroll
    for (int e = 0; e < 8; ++e) { s0[e] = EXP2F((s0[e] - m) * LOG2E); sm += s0[e]; }
    #pragma unroll
    for (int o2 = 32; o2; o2 >>= 1) sm += __shfl_xor(sm, o2);
    float inv = RCPF(sm);
    // write p for THIS wave's j-quarter (lanes [16w,16w+16) own j=[128w,128w+128))
    if ((l >> 4) == w) {
        float4 r0 = {s0[0] * inv, s0[1] * inv, s0[2] * inv, s0[3] * inv};
        float4 r1 = {s0[4] * inv, s0[5] * inv, s0[6] * inv, s0[7] * inv};
        *(float4*)(sP + l * 8) = r0;
        *(float4*)(sP + l * 8 + 4) = r1;
    }
    asm volatile("s_waitcnt lgkmcnt(0)" ::: "memory");   // wave-private RAW on own quarter

    // ---- agg partial over this wave's 128 j's ----
    {
        const int rs = l >> 3, c8 = (l & 7) * 8;
        float a8[8];
        #pragma unroll
        for (int e = 0; e < 8; ++e) a8[e] = 0.f;
        #pragma unroll 4
        for (int jb = 0; jb < 16; ++jb) {
            int j = w * 128 + jb * 8 + rs;
            float pj = sP[j];
            bf16x8 v = *(const bf16x8*)(Xg + j * 64 + c8);
            #pragma unroll
            for (int e = 0; e < 8; ++e)
                a8[e] = fmaf(bf2f((unsigned short)v[e]), pj, a8[e]);
        }
        #pragma unroll
        for (int e = 0; e < 8; ++e) {
            float v = a8[e];
            v += __shfl_xor(v, 8);
            v += __shfl_xor(v, 16);
            v += __shfl_xor(v, 32);
            a8[e] = v;
        }
        if (l < 8) {
            #pragma unroll
            for (int e = 0; e < 8; ++e) sAgP[w * 64 + l * 8 + e] = a8[e];
        }
    }
    __syncthreads();                 // barrier 2: all agg partials in LDS

    // ---- epilogue on wave 0: h[o=l] = agg@W_pa + x_i@W_po + biases ; BN ; SELU ----
    if (w == 0) {
        float hv = b_pa[l] + b_po[l];
        const float* wa = Wpat + l * 64;
        const float* wo = Wpot + l * 64;
        #pragma unroll 4
        for (int dc = 0; dc < 16; ++dc) {
            float4 g0 = *(const float4*)(sAgP +       dc * 4);
            float4 g1 = *(const float4*)(sAgP +  64 + dc * 4);
            float4 g2 = *(const float4*)(sAgP + 128 + dc * 4);
            float4 g3 = *(const float4*)(sAgP + 192 + dc * 4);
            float4 ag = {g0.x + g1.x + g2.x + g3.x, g0.y + g1.y + g2.y + g3.y,
                         g0.z + g1.z + g2.z + g3.z, g0.w + g1.w + g2.w + g3.w};
            float4 va = *(const float4*)(wa + dc * 4);
            float4 vo = *(const float4*)(wo + dc * 4);
            float4 xv = *(const float4*)(xi + dc * 4);
            hv = fmaf(ag.x, va.x, hv); hv = fmaf(ag.y, va.y, hv);
            hv = fmaf(ag.z, va.z, hv); hv = fmaf(ag.w, va.w, hv);
            hv = fmaf(xv.x, vo.x, hv); hv = fmaf(xv.y, vo.y, hv);
            hv = fmaf(xv.z, vo.z, hv); hv = fmaf(xv.w, vo.w, hv);
        }
        float istd = rsqrtf(rvar[l] + 1e-5f);
        hv = (hv - rmean[l]) * istd * gma[l] + bta[l];
        const float alpha = 1.6732632423543772f, scale = 1.0507009873554805f;
        float neg = alpha * (EXP2F(hv * LOG2E) - 1.0f);
        out[(size_t)ig * 64 + l] = scale * (hv > 0.f ? hv : neg);
    }
}

extern "C" void kernel_launch(void* const* d_in, const int* in_sizes, int n_in,
                              void* d_out, int out_size, void* d_ws, size_t ws_size,
                              hipStream_t stream) {
    const float* x     = (const float*)d_in[0];
    const float* W_ap  = (const float*)d_in[1];
    const float* b_ap  = (const float*)d_in[2];
    const float* att_w = (const float*)d_in[3];
    const float* W_pa  = (const float*)d_in[4];
    const float* b_pa  = (const float*)d_in[5];
    const float* W_po  = (const float*)d_in[6];
    const float* b_po  = (const float*)d_in[7];
    const float* gma   = (const float*)d_in[8];
    const float* bta   = (const float*)d_in[9];
    const float* rmean = (const float*)d_in[10];
    const float* rvar  = (const float*)d_in[11];

    char* ws = (char*)d_ws;
    unsigned short* Xb = (unsigned short*)ws;          // 512 KB bf16 X
    float* Wt          = (float*)(ws + 512 * 1024);    // 16 KB W_ap^T
    float* Wpat        = (float*)(ws + 528 * 1024);    // 16 KB W_pa^T
    float* Wpot        = (float*)(ws + 544 * 1024);    // 16 KB W_po^T
    float* out         = (float*)d_out;

    prep_kernel<<<128, 256, 0, stream>>>(x, W_ap, W_pa, W_po, Xb, Wt, Wpat, Wpot);
    gat_kernel<<<4096, 256, 0, stream>>>(x, b_ap, att_w, b_pa, b_po, gma, bta, rmean, rvar,
                                         Xb, Wt, Wpat, Wpot, out);
}

// Round 8
// 110.925 us; speedup vs baseline: 2.1590x; 1.4059x over previous
//
#include <hip/hip_runtime.h>
#include <cstdint>

typedef __attribute__((ext_vector_type(8))) short bf16x8;
typedef __attribute__((ext_vector_type(4))) float f32x4;

#if __has_builtin(__builtin_amdgcn_exp2f)
#define EXP2F(x) __builtin_amdgcn_exp2f(x)
#else
#define EXP2F(x) exp2f(x)
#endif
#if __has_builtin(__builtin_amdgcn_rcpf)
#define RCPF(x) __builtin_amdgcn_rcpf(x)
#else
#define RCPF(x) (1.0f/(x))
#endif

#define C2LOG2E 2.885390081777927f   // 2*log2(e)
#define LOG2E   1.4426950408889634f

__device__ __forceinline__ unsigned int f2bf(float f) {
    union { float f; unsigned int u; } v; v.f = f;
    return ((v.u + 0x7FFFu + ((v.u >> 16) & 1u)) >> 16);
}
__device__ __forceinline__ float bf2f(unsigned short h) {
    union { unsigned int u; float f; } v; v.u = ((unsigned int)h) << 16; return v.f;
}

// ---- prep: X fp32->bf16 ; transpose W_ap, W_pa, W_po ----
__global__ void prep_kernel(const float* __restrict__ x, const float* __restrict__ W_ap,
                            const float* __restrict__ W_pa, const float* __restrict__ W_po,
                            unsigned short* __restrict__ Xb, float* __restrict__ Wt,
                            float* __restrict__ Wpat, float* __restrict__ Wpot) {
    int t = blockIdx.x * 256 + threadIdx.x;   // 32768 threads, 8 elems each
    const float* src = x + (size_t)t * 8;
    float4 a = *(const float4*)(src);
    float4 b = *(const float4*)(src + 4);
    unsigned int p0 = f2bf(a.x) | (f2bf(a.y) << 16);
    unsigned int p1 = f2bf(a.z) | (f2bf(a.w) << 16);
    unsigned int p2 = f2bf(b.x) | (f2bf(b.y) << 16);
    unsigned int p3 = f2bf(b.z) | (f2bf(b.w) << 16);
    *(int4*)(Xb + (size_t)t * 8) = make_int4((int)p0, (int)p1, (int)p2, (int)p3);
    if (t < 64 * 64) {
        int src_i = (t & 63) * 64 + (t >> 6);   // [d][o] -> [o][d]
        Wt[t]   = W_ap[src_i];
        Wpat[t] = W_pa[src_i];
        Wpot[t] = W_po[src_i];
    }
}

// ---- main: one block per (b,i); 4 waves split over j (8 tiles each); 2 barriers.
// launch_bounds(256,5): 102-reg cap >= the ~95-reg R4-style body -> no spills
// (R5's 64-reg cap spilled; R6's 32-reg body choked the load pipeline).
__global__ __launch_bounds__(256, 5) void gat_kernel(
    const float* __restrict__ x, const float* __restrict__ b_ap, const float* __restrict__ att_w,
    const float* __restrict__ b_pa, const float* __restrict__ b_po,
    const float* __restrict__ gma, const float* __restrict__ bta,
    const float* __restrict__ rmean, const float* __restrict__ rvar,
    const unsigned short* __restrict__ Xb, const float* __restrict__ Wt,
    const float* __restrict__ Wpat, const float* __restrict__ Wpot,
    float* __restrict__ out)
{
    __shared__ float sSc[512];       // raw scores (block-shared)
    __shared__ float sP[512];        // normalized p (separate buffer: no read/write race)
    __shared__ float sAgP[4 * 64];   // per-wave agg partials

    const int t  = threadIdx.x;
    const int l  = t & 63;
    const int w  = t >> 6;
    // XCD swizzle: all blocks on one XCD share one batch b -> X_b L2-hot per XCD
    const int bid = blockIdx.x;
    const int ig  = (bid & 7) * 512 + (bid >> 3);   // global i in [0,4096)
    const int b   = ig >> 9;
    const int lm = l & 15;
    const int lq = l >> 4;
    const unsigned short* __restrict__ Xg = Xb + (size_t)b * (512 * 64);
    const float* __restrict__ xi = x + (size_t)ig * 64;

    // ---- A-fragments (W_i^T) in-register (redundant per wave, L1-hot) ----
    bf16x8 af[8];
    #pragma unroll
    for (int ks = 0; ks < 2; ++ks) {
        float4 xc0 = *(const float4*)(xi + ks * 32 + lq * 8);
        float4 xc1 = *(const float4*)(xi + ks * 32 + lq * 8 + 4);
        #pragma unroll
        for (int of = 0; of < 4; ++of) {
            const float* wr = Wt + (of * 16 + lm) * 64 + ks * 32 + lq * 8;
            float4 w0 = *(const float4*)(wr);
            float4 w1 = *(const float4*)(wr + 4);
            unsigned int p0 = f2bf(w0.x * xc0.x) | (f2bf(w0.y * xc0.y) << 16);
            unsigned int p1 = f2bf(w0.z * xc0.z) | (f2bf(w0.w * xc0.w) << 16);
            unsigned int p2 = f2bf(w1.x * xc1.x) | (f2bf(w1.y * xc1.y) << 16);
            unsigned int p3 = f2bf(w1.z * xc1.z) | (f2bf(w1.w * xc1.w) << 16);
            int4 pk = make_int4((int)p0, (int)p1, (int)p2, (int)p3);
            af[of * 2 + ks] = *reinterpret_cast<bf16x8*>(&pk);
        }
    }

    // ---- per-lane o-constants (o = of*16 + lq*4 + r) ----
    float n2a[16], cb[16];
    float asum = 0.f;
    #pragma unroll
    for (int of = 0; of < 4; ++of) {
        #pragma unroll
        for (int r = 0; r < 4; ++r) {
            int o = of * 16 + lq * 4 + r;
            float a = att_w[o];
            n2a[of * 4 + r] = -2.f * a;
            cb[of * 4 + r]  = C2LOG2E * b_ap[o];
            asum += a;
        }
    }

    // ---- GEMM + tanh-score: this wave's 8 j-tiles [8w, 8w+8) ----
    const unsigned short* xrow = Xg + lm * 64 + lq * 8;
    const int jt0 = w * 8;
    #pragma unroll 2
    for (int jj = 0; jj < 8; ++jj) {
        int jt = jt0 + jj;
        bf16x8 b0 = *(const bf16x8*)(xrow + jt * 1024);
        bf16x8 b1 = *(const bf16x8*)(xrow + jt * 1024 + 32);
        f32x4 acc[4];
        #pragma unroll
        for (int of = 0; of < 4; ++of) {
            acc[of] = (f32x4){0.f, 0.f, 0.f, 0.f};
            acc[of] = __builtin_amdgcn_mfma_f32_16x16x32_bf16(af[of * 2],     b0, acc[of], 0, 0, 0);
            acc[of] = __builtin_amdgcn_mfma_f32_16x16x32_bf16(af[of * 2 + 1], b1, acc[of], 0, 0, 0);
        }
        float p4[4];
        #pragma unroll
        for (int of = 0; of < 4; ++of) {
            float pp = 0.f;
            #pragma unroll
            for (int r = 0; r < 4; ++r) {
                float e = EXP2F(fmaf(acc[of][r], C2LOG2E, cb[of * 4 + r]));
                pp = fmaf(n2a[of * 4 + r], RCPF(1.f + e), pp);
            }
            p4[of] = pp;
        }
        float part = asum + ((p4[0] + p4[1]) + (p4[2] + p4[3]));
        part += __shfl_xor(part, 16);
        part += __shfl_xor(part, 32);
        if (l < 16) sSc[jt * 16 + l] = part;
    }
    __syncthreads();                 // barrier 1: all 512 scores in LDS

    // ---- softmax over 512 (redundant per wave; lane l holds j = l*8..l*8+7) ----
    float s0[8];
    {
        float4 r0 = *(const float4*)(sSc + l * 8);
        float4 r1 = *(const float4*)(sSc + l * 8 + 4);
        s0[0] = r0.x; s0[1] = r0.y; s0[2] = r0.z; s0[3] = r0.w;
        s0[4] = r1.x; s0[5] = r1.y; s0[6] = r1.z; s0[7] = r1.w;
    }
    float m = s0[0];
    #pragma unroll
    for (int e = 1; e < 8; ++e) m = fmaxf(m, s0[e]);
    #pragma unroll
    for (int o2 = 32; o2; o2 >>= 1) m = fmaxf(m, __shfl_xor(m, o2));
    float sm = 0.f;
    #pragma unroll
    for (int e = 0; e < 8; ++e) { s0[e] = EXP2F((s0[e] - m) * LOG2E); sm += s0[e]; }
    #pragma unroll
    for (int o2 = 32; o2; o2 >>= 1) sm += __shfl_xor(sm, o2);
    float inv = RCPF(sm);
    // write p for THIS wave's j-quarter (lanes [16w,16w+16) own j=[128w,128w+128))
    if ((l >> 4) == w) {
        float4 r0 = {s0[0] * inv, s0[1] * inv, s0[2] * inv, s0[3] * inv};
        float4 r1 = {s0[4] * inv, s0[5] * inv, s0[6] * inv, s0[7] * inv};
        *(float4*)(sP + l * 8) = r0;
        *(float4*)(sP + l * 8 + 4) = r1;
    }
    asm volatile("s_waitcnt lgkmcnt(0)" ::: "memory");   // wave-private RAW on own quarter

    // ---- agg partial over this wave's 128 j's ----
    {
        const int rs = l >> 3, c8 = (l & 7) * 8;
        float a8[8];
        #pragma unroll
        for (int e = 0; e < 8; ++e) a8[e] = 0.f;
        #pragma unroll 4
        for (int jb = 0; jb < 16; ++jb) {
            int j = w * 128 + jb * 8 + rs;
            float pj = sP[j];
            bf16x8 v = *(const bf16x8*)(Xg + j * 64 + c8);
            #pragma unroll
            for (int e = 0; e < 8; ++e)
                a8[e] = fmaf(bf2f((unsigned short)v[e]), pj, a8[e]);
        }
        #pragma unroll
        for (int e = 0; e < 8; ++e) {
            float v = a8[e];
            v += __shfl_xor(v, 8);
            v += __shfl_xor(v, 16);
            v += __shfl_xor(v, 32);
            a8[e] = v;
        }
        if (l < 8) {
            #pragma unroll
            for (int e = 0; e < 8; ++e) sAgP[w * 64 + l * 8 + e] = a8[e];
        }
    }
    __syncthreads();                 // barrier 2: all agg partials in LDS

    // ---- epilogue on wave 0: h[o=l] = agg@W_pa + x_i@W_po + biases ; BN ; SELU ----
    if (w == 0) {
        float hv = b_pa[l] + b_po[l];
        const float* wa = Wpat + l * 64;
        const float* wo = Wpot + l * 64;
        #pragma unroll 4
        for (int dc = 0; dc < 16; ++dc) {
            float4 g0 = *(const float4*)(sAgP +       dc * 4);
            float4 g1 = *(const float4*)(sAgP +  64 + dc * 4);
            float4 g2 = *(const float4*)(sAgP + 128 + dc * 4);
            float4 g3 = *(const float4*)(sAgP + 192 + dc * 4);
            float4 ag = {g0.x + g1.x + g2.x + g3.x, g0.y + g1.y + g2.y + g3.y,
                         g0.z + g1.z + g2.z + g3.z, g0.w + g1.w + g2.w + g3.w};
            float4 va = *(const float4*)(wa + dc * 4);
            float4 vo = *(const float4*)(wo + dc * 4);
            float4 xv = *(const float4*)(xi + dc * 4);
            hv = fmaf(ag.x, va.x, hv); hv = fmaf(ag.y, va.y, hv);
            hv = fmaf(ag.z, va.z, hv); hv = fmaf(ag.w, va.w, hv);
            hv = fmaf(xv.x, vo.x, hv); hv = fmaf(xv.y, vo.y, hv);
            hv = fmaf(xv.z, vo.z, hv); hv = fmaf(xv.w, vo.w, hv);
        }
        float istd = rsqrtf(rvar[l] + 1e-5f);
        hv = (hv - rmean[l]) * istd * gma[l] + bta[l];
        const float alpha = 1.6732632423543772f, scale = 1.0507009873554805f;
        float neg = alpha * (EXP2F(hv * LOG2E) - 1.0f);
        out[(size_t)ig * 64 + l] = scale * (hv > 0.f ? hv : neg);
    }
}

extern "C" void kernel_launch(void* const* d_in, const int* in_sizes, int n_in,
                              void* d_out, int out_size, void* d_ws, size_t ws_size,
                              hipStream_t stream) {
    const float* x     = (const float*)d_in[0];
    const float* W_ap  = (const float*)d_in[1];
    const float* b_ap  = (const float*)d_in[2];
    const float* att_w = (const float*)d_in[3];
    const float* W_pa  = (const float*)d_in[4];
    const float* b_pa  = (const float*)d_in[5];
    const float* W_po  = (const float*)d_in[6];
    const float* b_po  = (const float*)d_in[7];
    const float* gma   = (const float*)d_in[8];
    const float* bta   = (const float*)d_in[9];
    const float* rmean = (const float*)d_in[10];
    const float* rvar  = (const float*)d_in[11];

    char* ws = (char*)d_ws;
    unsigned short* Xb = (unsigned short*)ws;          // 512 KB bf16 X
    float* Wt          = (float*)(ws + 512 * 1024);    // 16 KB W_ap^T
    float* Wpat        = (float*)(ws + 528 * 1024);    // 16 KB W_pa^T
    float* Wpot        = (float*)(ws + 544 * 1024);    // 16 KB W_po^T
    float* out         = (float*)d_out;

    prep_kernel<<<128, 256, 0, stream>>>(x, W_ap, W_pa, W_po, Xb, Wt, Wpat, Wpot);
    gat_kernel<<<4096, 256, 0, stream>>>(x, b_ap, att_w, b_pa, b_po, gma, bta, rmean, rvar,
                                         Xb, Wt, Wpat, Wpot, out);
}

// Round 9
// 96.346 us; speedup vs baseline: 2.4857x; 1.1513x over previous
//
#include <hip/hip_runtime.h>
#include <cstdint>

typedef __attribute__((ext_vector_type(8))) short bf16x8;
typedef __attribute__((ext_vector_type(4))) float f32x4;

#if __has_builtin(__builtin_amdgcn_exp2f)
#define EXP2F(x) __builtin_amdgcn_exp2f(x)
#else
#define EXP2F(x) exp2f(x)
#endif
#if __has_builtin(__builtin_amdgcn_rcpf)
#define RCPF(x) __builtin_amdgcn_rcpf(x)
#else
#define RCPF(x) (1.0f/(x))
#endif

#define C2LOG2E 2.885390081777927f   // 2*log2(e)
#define LOG2E   1.4426950408889634f

__device__ __forceinline__ unsigned int f2bf(float f) {
    union { float f; unsigned int u; } v; v.f = f;
    return ((v.u + 0x7FFFu + ((v.u >> 16) & 1u)) >> 16);
}
__device__ __forceinline__ float bf2f(unsigned short h) {
    union { unsigned int u; float f; } v; v.u = ((unsigned int)h) << 16; return v.f;
}

// ---- prep: X fp32->bf16 ; transpose W_ap, W_pa, W_po ----
__global__ void prep_kernel(const float* __restrict__ x, const float* __restrict__ W_ap,
                            const float* __restrict__ W_pa, const float* __restrict__ W_po,
                            unsigned short* __restrict__ Xb, float* __restrict__ Wt,
                            float* __restrict__ Wpat, float* __restrict__ Wpot) {
    int t = blockIdx.x * 256 + threadIdx.x;   // 32768 threads, 8 elems each
    const float* src = x + (size_t)t * 8;
    float4 a = *(const float4*)(src);
    float4 b = *(const float4*)(src + 4);
    unsigned int p0 = f2bf(a.x) | (f2bf(a.y) << 16);
    unsigned int p1 = f2bf(a.z) | (f2bf(a.w) << 16);
    unsigned int p2 = f2bf(b.x) | (f2bf(b.y) << 16);
    unsigned int p3 = f2bf(b.z) | (f2bf(b.w) << 16);
    *(int4*)(Xb + (size_t)t * 8) = make_int4((int)p0, (int)p1, (int)p2, (int)p3);
    if (t < 64 * 64) {
        int src_i = (t & 63) * 64 + (t >> 6);   // [d][o] -> [o][d]
        Wt[t]   = W_ap[src_i];
        Wpat[t] = W_pa[src_i];
        Wpot[t] = W_po[src_i];
    }
}

__device__ __forceinline__ void build_af(bf16x8* af, const float* __restrict__ xi,
                                         const float* __restrict__ Wt, int lm, int lq) {
    #pragma unroll
    for (int ks = 0; ks < 2; ++ks) {
        float4 xc0 = *(const float4*)(xi + ks * 32 + lq * 8);
        float4 xc1 = *(const float4*)(xi + ks * 32 + lq * 8 + 4);
        #pragma unroll
        for (int of = 0; of < 4; ++of) {
            const float* wr = Wt + (of * 16 + lm) * 64 + ks * 32 + lq * 8;
            float4 w0 = *(const float4*)(wr);
            float4 w1 = *(const float4*)(wr + 4);
            unsigned int p0 = f2bf(w0.x * xc0.x) | (f2bf(w0.y * xc0.y) << 16);
            unsigned int p1 = f2bf(w0.z * xc0.z) | (f2bf(w0.w * xc0.w) << 16);
            unsigned int p2 = f2bf(w1.x * xc1.x) | (f2bf(w1.y * xc1.y) << 16);
            unsigned int p3 = f2bf(w1.z * xc1.z) | (f2bf(w1.w * xc1.w) << 16);
            int4 pk = make_int4((int)p0, (int)p1, (int)p2, (int)p3);
            af[of * 2 + ks] = *reinterpret_cast<bf16x8*>(&pk);
        }
    }
}

// ---- main: one block per i-PAIR (2 consecutive i's, same batch); 4 waves j-split.
// launch_bounds(256,4): 128-reg cap; body sized ~110 regs (acc held to 16 via
// of-pairing; b-frags + score consts shared across the 2 i's). Spill tripwire:
// WRITE_SIZE must stay ~1 MB.
__global__ __launch_bounds__(256, 4) void gat_kernel(
    const float* __restrict__ x, const float* __restrict__ b_ap, const float* __restrict__ att_w,
    const float* __restrict__ b_pa, const float* __restrict__ b_po,
    const float* __restrict__ gma, const float* __restrict__ bta,
    const float* __restrict__ rmean, const float* __restrict__ rvar,
    const unsigned short* __restrict__ Xb, const float* __restrict__ Wt,
    const float* __restrict__ Wpat, const float* __restrict__ Wpot,
    float* __restrict__ out)
{
    __shared__ float sSc[2][512];    // raw scores per i
    __shared__ float sP[2][512];     // normalized p per i (separate: no R/W race)
    __shared__ float sAgP[2][256];   // per-wave agg partials per i

    const int t  = threadIdx.x;
    const int l  = t & 63;
    const int w  = t >> 6;
    // XCD swizzle: 2048 blocks = 8 XCD x 256; XCD k <-> batch k (X_b L2-resident/XCD)
    const int bid = blockIdx.x;
    const int q   = (bid & 7) * 256 + (bid >> 3);   // pair index in [0,2048)
    const int b   = q >> 8;
    const int i0  = q * 2;                          // both i's in batch b
    const int lm = l & 15;
    const int lq = l >> 4;
    const unsigned short* __restrict__ Xg = Xb + (size_t)b * (512 * 64);
    const float* __restrict__ xi0 = x + (size_t)i0 * 64;
    const float* __restrict__ xi1 = xi0 + 64;

    // ---- A-fragments for both i's ----
    bf16x8 af0[8], af1[8];
    build_af(af0, xi0, Wt, lm, lq);
    build_af(af1, xi1, Wt, lm, lq);

    // ---- per-lane o-constants (o = of*16 + lq*4 + r), shared across i's ----
    float n2a[16], cb[16];
    float asum = 0.f;
    #pragma unroll
    for (int of = 0; of < 4; ++of) {
        #pragma unroll
        for (int r = 0; r < 4; ++r) {
            int o = of * 16 + lq * 4 + r;
            float a = att_w[o];
            n2a[of * 4 + r] = -2.f * a;
            cb[of * 4 + r]  = C2LOG2E * b_ap[o];
            asum += a;
        }
    }

    // ---- QK + tanh-score: this wave's 8 j-tiles, BOTH i's (shared b-frags) ----
    const unsigned short* xrow = Xg + lm * 64 + lq * 8;
    const int jt0 = w * 8;
    for (int jj = 0; jj < 8; ++jj) {
        int jt = jt0 + jj;
        bf16x8 b0 = *(const bf16x8*)(xrow + jt * 1024);
        bf16x8 b1 = *(const bf16x8*)(xrow + jt * 1024 + 32);
        float part0 = asum, part1 = asum;
        #pragma unroll
        for (int ofp = 0; ofp < 2; ++ofp) {
            const int of0 = ofp * 2, of1 = ofp * 2 + 1;
            f32x4 a00 = (f32x4){0.f,0.f,0.f,0.f}, a01 = (f32x4){0.f,0.f,0.f,0.f};
            f32x4 a10 = (f32x4){0.f,0.f,0.f,0.f}, a11 = (f32x4){0.f,0.f,0.f,0.f};
            a00 = __builtin_amdgcn_mfma_f32_16x16x32_bf16(af0[of0*2],   b0, a00, 0,0,0);
            a01 = __builtin_amdgcn_mfma_f32_16x16x32_bf16(af0[of1*2],   b0, a01, 0,0,0);
            a10 = __builtin_amdgcn_mfma_f32_16x16x32_bf16(af1[of0*2],   b0, a10, 0,0,0);
            a11 = __builtin_amdgcn_mfma_f32_16x16x32_bf16(af1[of1*2],   b0, a11, 0,0,0);
            a00 = __builtin_amdgcn_mfma_f32_16x16x32_bf16(af0[of0*2+1], b1, a00, 0,0,0);
            a01 = __builtin_amdgcn_mfma_f32_16x16x32_bf16(af0[of1*2+1], b1, a01, 0,0,0);
            a10 = __builtin_amdgcn_mfma_f32_16x16x32_bf16(af1[of0*2+1], b1, a10, 0,0,0);
            a11 = __builtin_amdgcn_mfma_f32_16x16x32_bf16(af1[of1*2+1], b1, a11, 0,0,0);
            #pragma unroll
            for (int r = 0; r < 4; ++r) {
                float e00 = EXP2F(fmaf(a00[r], C2LOG2E, cb[of0*4+r]));
                part0 = fmaf(n2a[of0*4+r], RCPF(1.f + e00), part0);
                float e01 = EXP2F(fmaf(a01[r], C2LOG2E, cb[of1*4+r]));
                part0 = fmaf(n2a[of1*4+r], RCPF(1.f + e01), part0);
                float e10 = EXP2F(fmaf(a10[r], C2LOG2E, cb[of0*4+r]));
                part1 = fmaf(n2a[of0*4+r], RCPF(1.f + e10), part1);
                float e11 = EXP2F(fmaf(a11[r], C2LOG2E, cb[of1*4+r]));
                part1 = fmaf(n2a[of1*4+r], RCPF(1.f + e11), part1);
            }
        }
        part0 += __shfl_xor(part0, 16);
        part0 += __shfl_xor(part0, 32);
        part1 += __shfl_xor(part1, 16);
        part1 += __shfl_xor(part1, 32);
        if (l < 16) {
            sSc[0][jt * 16 + l] = part0;
            sSc[1][jt * 16 + l] = part1;
        }
    }
    __syncthreads();                 // barrier 1: all scores (both i's) in LDS

    // ---- softmax over 512, both i's (redundant per wave) ----
    #pragma unroll
    for (int ii = 0; ii < 2; ++ii) {
        float s0[8];
        {
            float4 r0 = *(const float4*)(&sSc[ii][l * 8]);
            float4 r1 = *(const float4*)(&sSc[ii][l * 8 + 4]);
            s0[0]=r0.x; s0[1]=r0.y; s0[2]=r0.z; s0[3]=r0.w;
            s0[4]=r1.x; s0[5]=r1.y; s0[6]=r1.z; s0[7]=r1.w;
        }
        float m = s0[0];
        #pragma unroll
        for (int e = 1; e < 8; ++e) m = fmaxf(m, s0[e]);
        #pragma unroll
        for (int o2 = 32; o2; o2 >>= 1) m = fmaxf(m, __shfl_xor(m, o2));
        float sm = 0.f;
        #pragma unroll
        for (int e = 0; e < 8; ++e) { s0[e] = EXP2F((s0[e] - m) * LOG2E); sm += s0[e]; }
        #pragma unroll
        for (int o2 = 32; o2; o2 >>= 1) sm += __shfl_xor(sm, o2);
        float inv = RCPF(sm);
        // write p for THIS wave's j-quarter (lanes [16w,16w+16) own j=[128w,128w+128))
        if ((l >> 4) == w) {
            float4 r0 = {s0[0]*inv, s0[1]*inv, s0[2]*inv, s0[3]*inv};
            float4 r1 = {s0[4]*inv, s0[5]*inv, s0[6]*inv, s0[7]*inv};
            *(float4*)(&sP[ii][l * 8]) = r0;
            *(float4*)(&sP[ii][l * 8 + 4]) = r1;
        }
    }
    asm volatile("s_waitcnt lgkmcnt(0)" ::: "memory");   // wave-private RAW on own quarter

    // ---- agg partial over this wave's 128 j's, both i's (X row loaded once) ----
    {
        const int rs = l >> 3, c8 = (l & 7) * 8;
        float a80[8], a81[8];
        #pragma unroll
        for (int e = 0; e < 8; ++e) { a80[e] = 0.f; a81[e] = 0.f; }
        #pragma unroll 4
        for (int jb = 0; jb < 16; ++jb) {
            int j = w * 128 + jb * 8 + rs;
            float p0 = sP[0][j];
            float p1 = sP[1][j];
            bf16x8 v = *(const bf16x8*)(Xg + j * 64 + c8);
            #pragma unroll
            for (int e = 0; e < 8; ++e) {
                float f = bf2f((unsigned short)v[e]);
                a80[e] = fmaf(f, p0, a80[e]);
                a81[e] = fmaf(f, p1, a81[e]);
            }
        }
        #pragma unroll
        for (int e = 0; e < 8; ++e) {
            float v0 = a80[e], v1 = a81[e];
            v0 += __shfl_xor(v0, 8);  v1 += __shfl_xor(v1, 8);
            v0 += __shfl_xor(v0, 16); v1 += __shfl_xor(v1, 16);
            v0 += __shfl_xor(v0, 32); v1 += __shfl_xor(v1, 32);
            a80[e] = v0; a81[e] = v1;
        }
        if (l < 8) {
            #pragma unroll
            for (int e = 0; e < 8; ++e) {
                sAgP[0][w * 64 + l * 8 + e] = a80[e];
                sAgP[1][w * 64 + l * 8 + e] = a81[e];
            }
        }
    }
    __syncthreads();                 // barrier 2: all agg partials in LDS

    // ---- epilogue: wave 0 -> i0, wave 1 -> i1 ----
    if (w < 2) {
        const float* xiw = (w == 0) ? xi0 : xi1;
        float hv = b_pa[l] + b_po[l];
        const float* wa = Wpat + l * 64;
        const float* wo = Wpot + l * 64;
        #pragma unroll 4
        for (int dc = 0; dc < 16; ++dc) {
            float4 g0 = *(const float4*)(&sAgP[w][      dc * 4]);
            float4 g1 = *(const float4*)(&sAgP[w][ 64 + dc * 4]);
            float4 g2 = *(const float4*)(&sAgP[w][128 + dc * 4]);
            float4 g3 = *(const float4*)(&sAgP[w][192 + dc * 4]);
            float4 ag = {g0.x+g1.x+g2.x+g3.x, g0.y+g1.y+g2.y+g3.y,
                         g0.z+g1.z+g2.z+g3.z, g0.w+g1.w+g2.w+g3.w};
            float4 va = *(const float4*)(wa + dc * 4);
            float4 vo = *(const float4*)(wo + dc * 4);
            float4 xv = *(const float4*)(xiw + dc * 4);
            hv = fmaf(ag.x, va.x, hv); hv = fmaf(ag.y, va.y, hv);
            hv = fmaf(ag.z, va.z, hv); hv = fmaf(ag.w, va.w, hv);
            hv = fmaf(xv.x, vo.x, hv); hv = fmaf(xv.y, vo.y, hv);
            hv = fmaf(xv.z, vo.z, hv); hv = fmaf(xv.w, vo.w, hv);
        }
        float istd = rsqrtf(rvar[l] + 1e-5f);
        hv = (hv - rmean[l]) * istd * gma[l] + bta[l];
        const float alpha = 1.6732632423543772f, scale = 1.0507009873554805f;
        float neg = alpha * (EXP2F(hv * LOG2E) - 1.0f);
        out[((size_t)(i0 + w)) * 64 + l] = scale * (hv > 0.f ? hv : neg);
    }
}

extern "C" void kernel_launch(void* const* d_in, const int* in_sizes, int n_in,
                              void* d_out, int out_size, void* d_ws, size_t ws_size,
                              hipStream_t stream) {
    const float* x     = (const float*)d_in[0];
    const float* W_ap  = (const float*)d_in[1];
    const float* b_ap  = (const float*)d_in[2];
    const float* att_w = (const float*)d_in[3];
    const float* W_pa  = (const float*)d_in[4];
    const float* b_pa  = (const float*)d_in[5];
    const float* W_po  = (const float*)d_in[6];
    const float* b_po  = (const float*)d_in[7];
    const float* gma   = (const float*)d_in[8];
    const float* bta   = (const float*)d_in[9];
    const float* rmean = (const float*)d_in[10];
    const float* rvar  = (const float*)d_in[11];

    char* ws = (char*)d_ws;
    unsigned short* Xb = (unsigned short*)ws;          // 512 KB bf16 X
    float* Wt          = (float*)(ws + 512 * 1024);    // 16 KB W_ap^T
    float* Wpat        = (float*)(ws + 528 * 1024);    // 16 KB W_pa^T
    float* Wpot        = (float*)(ws + 544 * 1024);    // 16 KB W_po^T
    float* out         = (float*)d_out;

    prep_kernel<<<128, 256, 0, stream>>>(x, W_ap, W_pa, W_po, Xb, Wt, Wpat, Wpot);
    gat_kernel<<<2048, 256, 0, stream>>>(x, b_ap, att_w, b_pa, b_po, gma, bta, rmean, rvar,
                                         Xb, Wt, Wpat, Wpot, out);
}